// Round 9
// baseline (386.385 us; speedup 1.0000x reference)
//
#include <hip/hip_runtime.h>
#include <hip/hip_bf16.h>

typedef __attribute__((ext_vector_type(8))) __bf16 bf16x8;
typedef __attribute__((ext_vector_type(4))) float f32x4;
typedef __attribute__((ext_vector_type(8))) unsigned short ushort8;

#define TOKS 8192
#define LOG2E 1.4426950408889634f

// ============================================================================
// Kernel A: fused q/k/v per-blade projections.  4 tokens/block, o = tid.
// ============================================================================
__global__ __launch_bounds__(128) void proj_kernel(
    const float* __restrict__ x,
    const float* __restrict__ wq, const float* __restrict__ bq,
    const float* __restrict__ wk, const float* __restrict__ bk,
    const float* __restrict__ wv, const float* __restrict__ bv,
    __bf16* __restrict__ Qg, __bf16* __restrict__ Kg, __bf16* __restrict__ Vg)
{
    __shared__ float xs[512];
    const int tid = threadIdx.x;
    const int t0 = blockIdx.x * 4;
    ((float4*)xs)[tid] = ((const float4*)(x + (size_t)t0 * 128))[tid];
    __syncthreads();
    const int o = tid, h = o >> 4, d = o & 15;

    float acc[3][4][8];
#pragma unroll
    for (int tz = 0; tz < 3; ++tz) {
        const float bias = (tz == 0 ? bq : tz == 1 ? bk : bv)[o];
#pragma unroll
        for (int t = 0; t < 4; ++t) {
            acc[tz][t][0] = bias;
#pragma unroll
            for (int c = 1; c < 8; ++c) acc[tz][t][c] = 0.f;
        }
    }
    const float4* w40 = (const float4*)(wq + o * 64);
    const float4* w41 = (const float4*)(wk + o * 64);
    const float4* w42 = (const float4*)(wv + o * 64);
    for (int i = 0; i < 16; ++i) {
        float4 wv3[3] = {w40[i], w41[i], w42[i]};
#pragma unroll
        for (int t = 0; t < 4; ++t) {
            f32x4 xlo = *(const f32x4*)(xs + t * 128 + i * 8);
            f32x4 xhi = *(const f32x4*)(xs + t * 128 + i * 8 + 4);
            float xv[8] = {xlo[0], xlo[1], xlo[2], xlo[3],
                           xhi[0], xhi[1], xhi[2], xhi[3]};
#pragma unroll
            for (int tz = 0; tz < 3; ++tz) {
                float wr[8] = {wv3[tz].x, wv3[tz].y, wv3[tz].y, wv3[tz].y,
                               wv3[tz].z, wv3[tz].z, wv3[tz].z, wv3[tz].w};
#pragma unroll
                for (int c = 0; c < 8; ++c) acc[tz][t][c] += xv[c] * wr[c];
            }
        }
    }
    const int bb = t0 >> 11, tt0 = t0 & 2047;
    size_t base = (((size_t)(bb * 8 + h)) * 2048 + tt0) * 128 + d * 8;
#pragma unroll
    for (int tz = 0; tz < 3; ++tz) {
        __bf16* Og = tz == 0 ? Qg : tz == 1 ? Kg : Vg;
        const float scale = (tz == 0) ? 0.08838834764831845f : 1.0f;
#pragma unroll
        for (int t = 0; t < 4; ++t) {
            bf16x8 v;
#pragma unroll
            for (int c = 0; c < 8; ++c) v[c] = (__bf16)(acc[tz][t][c] * scale);
            *(bf16x8*)(Og + base + (size_t)t * 128) = v;
        }
    }
}

// ============================================================================
// Kernel A2: V [bh][t][e] -> Vt [bh][e][t] (64-token tiles, LDS swizzled).
// ============================================================================
__global__ __launch_bounds__(256) void transv_kernel(
    const __bf16* __restrict__ Vg, __bf16* __restrict__ Vt)
{
    __shared__ __align__(16) char T[16384];
    const int tid = threadIdx.x;
    const int bh = blockIdx.y, t0 = blockIdx.x * 64;
    const __bf16* src = Vg + ((size_t)bh * 2048 + t0) * 128;
#pragma unroll
    for (int it = 0; it < 4; ++it) {
        int cidx = it * 256 + tid;
        int r = cidx >> 4, e0 = (cidx & 15) * 8;
        bf16x8 v = *(const bf16x8*)(src + r * 128 + e0);
        *(bf16x8*)(T + ((r * 256 + e0 * 2) ^ ((r & 7) << 4))) = v;
    }
    __syncthreads();
    const int e = tid & 127, half = tid >> 7;
    __bf16* dst = Vt + ((size_t)bh * 128 + e) * 2048 + t0 + half * 32;
#pragma unroll
    for (int jc = 0; jc < 4; ++jc) {
        ushort8 o8;
#pragma unroll
        for (int j = 0; j < 8; ++j) {
            int t = half * 32 + jc * 8 + j;
            o8[j] = *(const unsigned short*)(T + ((t * 256 + e * 2) ^ ((t & 7) << 4)));
        }
        *(ushort8*)(dst + jc * 8) = o8;
    }
}

// ============================================================================
// Kernel B: flash attention, O^T form, fixed softmax reference (m = 0).
// V fragments loaded GLOBAL->REG at tile start (issued right after the
// barrier, consumed after QK+softmax ~600cy later; L2 is XCD-local and the
// 4 waves share the 16KB tile through L1). Vl/vreg deleted: LDS ops/tile
// drop 46->26. Freed LDS double-buffers Kl -> ONE barrier per tile.
// ============================================================================
__global__ __launch_bounds__(256) void flash_kernel(
    const __bf16* __restrict__ Qg, const __bf16* __restrict__ Kg,
    const __bf16* __restrict__ Vtg, const float* __restrict__ mask,
    __bf16* __restrict__ AO)
{
    __shared__ __align__(16) char Kl[2][16384]; // [64 kv][128 e], swz ((kv&7)<<4)
    __shared__ __align__(16) char Pl[8192];     // per-wave [16 q][64 kv], swz ((q&7)<<4)

    const int tid = threadIdx.x;
    const int lane = tid & 63, w = tid >> 6;
    const int l15 = lane & 15, lg = lane >> 4;

    // XCD-aware remap (r8): XCD x owns bh in {4x..4x+3} -> K/V stay in its L2.
    const int wid = blockIdx.y * 32 + blockIdx.x;
    const int xcd = wid & 7, j = wid >> 3;
    const int bh = (xcd << 2) | (j & 3);
    const int q0 = (j >> 2) * 64;
    const int b = bh >> 3;

    int kg[4], klb[4];
#pragma unroll
    for (int it = 0; it < 4; ++it) {
        int cidx = it * 256 + tid;
        int kv = cidx >> 4, c15 = cidx & 15;
        kg[it] = kv * 128 + c15 * 8;
        klb[it] = kv * 256 + ((c15 * 16) ^ ((kv & 7) << 4));
    }
    const __bf16* kbase = Kg + (size_t)bh * 2048 * 128;
    const __bf16* vtbase = Vtg + (size_t)bh * 128 * 2048;
    const float* mbase = mask + ((size_t)b * 2048 + q0 + w * 16 + l15) * 2048;
    // per-lane V base: e row l15 (of each 16-row block), kv chunk lg*8
    const __bf16* vlane = vtbase + (size_t)l15 * 2048 + lg * 8;

    bf16x8 qf[4];
    {
        const __bf16* qp = Qg + ((size_t)bh * 2048 + q0 + w * 16 + l15) * 128 + lg * 8;
#pragma unroll
        for (int ks = 0; ks < 4; ++ks) qf[ks] = *(const bf16x8*)(qp + ks * 32);
    }

    f32x4 o_acc[8];                    // O^T: [e-tile ct2][r], col q = l15
#pragma unroll
    for (int i = 0; i < 8; ++i) o_acc[i] = (f32x4){0.f, 0.f, 0.f, 0.f};
    float lacc = 0.f;                  // per-lane partial of row-l15 lsum
    const int pbase = w * 2048 + l15 * 128;
    const int psw = (l15 & 7) << 4;

    // prologue: stage K tile 0 into Kl[0]; mask tile 0 to regs
    bf16x8 kreg[4];
#pragma unroll
    for (int it = 0; it < 4; ++it) kreg[it] = *(const bf16x8*)(kbase + kg[it]);
#pragma unroll
    for (int it = 0; it < 4; ++it) *(bf16x8*)(Kl[0] + klb[it]) = kreg[it];
    f32x4 mr[4];
#pragma unroll
    for (int ct = 0; ct < 4; ++ct)
        mr[ct] = *(const f32x4*)(mbase + ct * 16 + lg * 4);

    int cur = 0;
    for (int kv0 = 0; kv0 < 2048; kv0 += 64) {
        __syncthreads();   // Kl[cur] staged (prev iter writes done, prev reads done)
        const bool more = (kv0 + 64) < 2048;

        // V fragments for THIS tile: issue now, consume after QK+softmax.
        const __bf16* vln = vlane + kv0;
        bf16x8 vfrag[16];
#pragma unroll
        for (int ct2 = 0; ct2 < 8; ++ct2) {
            vfrag[ct2 * 2]     = *(const bf16x8*)(vln + ct2 * 32768);
            vfrag[ct2 * 2 + 1] = *(const bf16x8*)(vln + ct2 * 32768 + 32);
        }
        if (more) {                            // next K tile to regs
            const __bf16* kb = kbase + (size_t)(kv0 + 64) * 128;
#pragma unroll
            for (int it = 0; it < 4; ++it) kreg[it] = *(const bf16x8*)(kb + kg[it]);
        }
        __builtin_amdgcn_sched_barrier(0);     // pin load-issue before QK

        // S^T = K Q^T : st[ct][r] is (q = l15, kv = ct*16 + lg*4 + r)
        f32x4 st[4];
        __builtin_amdgcn_s_setprio(1);
#pragma unroll
        for (int ct = 0; ct < 4; ++ct) {
            f32x4 acc = (f32x4){0.f, 0.f, 0.f, 0.f};
            const int kvr = ct * 16 + l15;
            const int rowb = kvr * 256, sw = (kvr & 7) << 4;
#pragma unroll
            for (int ks = 0; ks < 4; ++ks) {
                bf16x8 kf = *(const bf16x8*)(Kl[cur] + rowb + ((ks * 64 + lg * 16) ^ sw));
                acc = __builtin_amdgcn_mfma_f32_16x16x32_bf16(kf, qf[ks], acc, 0, 0, 0);
            }
            st[ct] = acc;
        }
        __builtin_amdgcn_s_setprio(0);

        // P = exp(s + mask), fixed reference 0; no cross-lane ops in-loop.
#pragma unroll
        for (int ct = 0; ct < 4; ++ct) {
            union { __bf16 h[4]; unsigned long long u64; } pk;
#pragma unroll
            for (int r = 0; r < 4; ++r) {
                float p = exp2f((st[ct][r] + mr[ct][r]) * LOG2E);
                lacc += p;
                pk.h[r] = (__bf16)p;
            }
            *(unsigned long long*)(Pl + pbase + ((ct * 32 + lg * 8) ^ psw)) = pk.u64;
        }

        // P write -> P read same-wave ordering (rule #18 fence)
        asm volatile("s_waitcnt lgkmcnt(0)" ::: "memory");
        __builtin_amdgcn_sched_barrier(0);

        // O^T += V^T P^T (V from registers; vmcnt wait auto-inserted)
        __builtin_amdgcn_s_setprio(1);
#pragma unroll
        for (int ks2 = 0; ks2 < 2; ++ks2) {
            bf16x8 pf = *(const bf16x8*)(Pl + pbase + ((ks2 * 64 + lg * 16) ^ psw));
#pragma unroll
            for (int ct2 = 0; ct2 < 8; ++ct2) {
                o_acc[ct2] = __builtin_amdgcn_mfma_f32_16x16x32_bf16(
                    vfrag[ct2 * 2 + ks2], pf, o_acc[ct2], 0, 0, 0);
            }
        }
        __builtin_amdgcn_s_setprio(0);

        if (more) {                            // stage next K into other buffer
#pragma unroll
            for (int it = 0; it < 4; ++it) *(bf16x8*)(Kl[cur ^ 1] + klb[it]) = kreg[it];
#pragma unroll
            for (int ct = 0; ct < 4; ++ct)
                mr[ct] = *(const f32x4*)(mbase + kv0 + 64 + ct * 16 + lg * 4);
        }
        cur ^= 1;
    }

    // epilogue: reduce lsum once (row q=l15 split over 4 lg lanes)
    float tot = lacc;
    tot += __shfl_xor(tot, 16);
    tot += __shfl_xor(tot, 32);
    const float linv = 1.0f / tot;
    const size_t tok = (size_t)b * 2048 + q0 + w * 16 + l15;
    __bf16* aop = AO + tok * 1024 + (bh & 7) * 128;
#pragma unroll
    for (int ct2 = 0; ct2 < 8; ++ct2) {
        union { __bf16 h[4]; unsigned long long u64; } ov;
#pragma unroll
        for (int r = 0; r < 4; ++r) ov.h[r] = (__bf16)(o_acc[ct2][r] * linv);
        *(unsigned long long*)(aop + ct2 * 16 + lg * 4) = ov.u64;
    }
}

// ============================================================================
// Kernel C: output projection. 8 tokens/block, thread = (o = tid>>3, t = tid&7).
// ============================================================================
__global__ __launch_bounds__(128) void outproj_kernel(
    const __bf16* __restrict__ AO, const float* __restrict__ wo,
    const float* __restrict__ bo, float* __restrict__ out)
{
    __shared__ float al[8 * 1032];
    const int tid = threadIdx.x;
    const int t0 = blockIdx.x * 8;
#pragma unroll
    for (int it = 0; it < 8; ++it) {
        bf16x8 v = *(const bf16x8*)(AO + (size_t)(t0 + it) * 1024 + tid * 8);
        f32x4 lo = {(float)v[0], (float)v[1], (float)v[2], (float)v[3]};
        f32x4 hi = {(float)v[4], (float)v[5], (float)v[6], (float)v[7]};
        *(f32x4*)(al + it * 1032 + tid * 8) = lo;
        *(f32x4*)(al + it * 1032 + tid * 8 + 4) = hi;
    }
    __syncthreads();
    const int o = tid >> 3, t = tid & 7;
    float acc[8];
    acc[0] = bo[o];
#pragma unroll
    for (int c = 1; c < 8; ++c) acc[c] = 0.f;
    const float4* w4 = (const float4*)wo + o * 128;
    for (int ii = 0; ii < 128; ++ii) {
        float4 wv = w4[ii];
        f32x4 xlo = *(const f32x4*)(al + t * 1032 + ii * 8);
        f32x4 xhi = *(const f32x4*)(al + t * 1032 + ii * 8 + 4);
        float wr[8] = {wv.x, wv.y, wv.y, wv.y, wv.z, wv.z, wv.z, wv.w};
        float xv[8] = {xlo[0], xlo[1], xlo[2], xlo[3], xhi[0], xhi[1], xhi[2], xhi[3]};
#pragma unroll
        for (int c = 0; c < 8; ++c) acc[c] += xv[c] * wr[c];
    }
    float* op = out + (size_t)(t0 + t) * 128 + o * 8;
    *(float4*)op = (float4){acc[0], acc[1], acc[2], acc[3]};
    *(float4*)(op + 4) = (float4){acc[4], acc[5], acc[6], acc[7]};
}

// ============================================================================
extern "C" void kernel_launch(void* const* d_in, const int* in_sizes, int n_in,
                              void* d_out, int out_size, void* d_ws, size_t ws_size,
                              hipStream_t stream)
{
    const float* x    = (const float*)d_in[0];
    const float* mask = (const float*)d_in[1];
    const float* wq   = (const float*)d_in[2];
    const float* bq   = (const float*)d_in[3];
    const float* wk   = (const float*)d_in[4];
    const float* bk   = (const float*)d_in[5];
    const float* wv   = (const float*)d_in[6];
    const float* bv   = (const float*)d_in[7];
    const float* wo   = (const float*)d_in[8];
    const float* bo   = (const float*)d_in[9];
    float* out = (float*)d_out;

    const size_t SLOT = (size_t)32 * 2048 * 128;  // 8M bf16 elems = 16 MiB
    const size_t need = SLOT * 4 * 2;             // 64 MiB
    if (ws_size < need) {
        hipMemsetAsync(d_out, 0, (size_t)out_size * sizeof(float), stream);
        return;
    }
    __bf16* Qg = (__bf16*)d_ws;
    __bf16* Kg = Qg + SLOT;
    __bf16* Vg = Kg + SLOT;   // V row-major; dead after transv
    __bf16* Vt = Vg + SLOT;
    __bf16* AO = Vg;          // reuse: flash writes AO only after Vg is dead

    proj_kernel<<<TOKS / 4, 128, 0, stream>>>(x, wq, bq, wk, bk, wv, bv, Qg, Kg, Vg);
    transv_kernel<<<dim3(32, 32), 256, 0, stream>>>(Vg, Vt);
    flash_kernel<<<dim3(32, 32), 256, 0, stream>>>(Qg, Kg, Vt, mask, AO);
    outproj_kernel<<<TOKS / 8, 128, 0, stream>>>(AO, wo, bo, out);
}

// Round 10
// 366.536 us; speedup vs baseline: 1.0542x; 1.0542x over previous
//
#include <hip/hip_runtime.h>
#include <hip/hip_bf16.h>

typedef __attribute__((ext_vector_type(8))) __bf16 bf16x8;
typedef __attribute__((ext_vector_type(4))) float f32x4;
typedef __attribute__((ext_vector_type(8))) unsigned short ushort8;

#define TOKS 8192
#define LOG2E 1.4426950408889634f

// async global->LDS 16B copy: LDS dest = wave-uniform base + lane*16
__device__ inline void gld16(const __bf16* g, void* l) {
    __builtin_amdgcn_global_load_lds(
        (const __attribute__((address_space(1))) unsigned int*)g,
        (__attribute__((address_space(3))) unsigned int*)l, 16, 0, 0);
}

// ============================================================================
// Kernel A: fused q/k/v per-blade projections.  4 tokens/block, o = tid.
// ============================================================================
__global__ __launch_bounds__(128) void proj_kernel(
    const float* __restrict__ x,
    const float* __restrict__ wq, const float* __restrict__ bq,
    const float* __restrict__ wk, const float* __restrict__ bk,
    const float* __restrict__ wv, const float* __restrict__ bv,
    __bf16* __restrict__ Qg, __bf16* __restrict__ Kg, __bf16* __restrict__ Vg)
{
    __shared__ float xs[512];
    const int tid = threadIdx.x;
    const int t0 = blockIdx.x * 4;
    ((float4*)xs)[tid] = ((const float4*)(x + (size_t)t0 * 128))[tid];
    __syncthreads();
    const int o = tid, h = o >> 4, d = o & 15;

    float acc[3][4][8];
#pragma unroll
    for (int tz = 0; tz < 3; ++tz) {
        const float bias = (tz == 0 ? bq : tz == 1 ? bk : bv)[o];
#pragma unroll
        for (int t = 0; t < 4; ++t) {
            acc[tz][t][0] = bias;
#pragma unroll
            for (int c = 1; c < 8; ++c) acc[tz][t][c] = 0.f;
        }
    }
    const float4* w40 = (const float4*)(wq + o * 64);
    const float4* w41 = (const float4*)(wk + o * 64);
    const float4* w42 = (const float4*)(wv + o * 64);
    for (int i = 0; i < 16; ++i) {
        float4 wv3[3] = {w40[i], w41[i], w42[i]};
#pragma unroll
        for (int t = 0; t < 4; ++t) {
            f32x4 xlo = *(const f32x4*)(xs + t * 128 + i * 8);
            f32x4 xhi = *(const f32x4*)(xs + t * 128 + i * 8 + 4);
            float xv[8] = {xlo[0], xlo[1], xlo[2], xlo[3],
                           xhi[0], xhi[1], xhi[2], xhi[3]};
#pragma unroll
            for (int tz = 0; tz < 3; ++tz) {
                float wr[8] = {wv3[tz].x, wv3[tz].y, wv3[tz].y, wv3[tz].y,
                               wv3[tz].z, wv3[tz].z, wv3[tz].z, wv3[tz].w};
#pragma unroll
                for (int c = 0; c < 8; ++c) acc[tz][t][c] += xv[c] * wr[c];
            }
        }
    }
    const int bb = t0 >> 11, tt0 = t0 & 2047;
    size_t base = (((size_t)(bb * 8 + h)) * 2048 + tt0) * 128 + d * 8;
#pragma unroll
    for (int tz = 0; tz < 3; ++tz) {
        __bf16* Og = tz == 0 ? Qg : tz == 1 ? Kg : Vg;
        const float scale = (tz == 0) ? 0.08838834764831845f : 1.0f;
#pragma unroll
        for (int t = 0; t < 4; ++t) {
            bf16x8 v;
#pragma unroll
            for (int c = 0; c < 8; ++c) v[c] = (__bf16)(acc[tz][t][c] * scale);
            *(bf16x8*)(Og + base + (size_t)t * 128) = v;
        }
    }
}

// ============================================================================
// Kernel A2: V [bh][t][e] -> Vt [bh][e][t] (64-token tiles, LDS swizzled).
// ============================================================================
__global__ __launch_bounds__(256) void transv_kernel(
    const __bf16* __restrict__ Vg, __bf16* __restrict__ Vt)
{
    __shared__ __align__(16) char T[16384];
    const int tid = threadIdx.x;
    const int bh = blockIdx.y, t0 = blockIdx.x * 64;
    const __bf16* src = Vg + ((size_t)bh * 2048 + t0) * 128;
#pragma unroll
    for (int it = 0; it < 4; ++it) {
        int cidx = it * 256 + tid;
        int r = cidx >> 4, e0 = (cidx & 15) * 8;
        bf16x8 v = *(const bf16x8*)(src + r * 128 + e0);
        *(bf16x8*)(T + ((r * 256 + e0 * 2) ^ ((r & 7) << 4))) = v;
    }
    __syncthreads();
    const int e = tid & 127, half = tid >> 7;
    __bf16* dst = Vt + ((size_t)bh * 128 + e) * 2048 + t0 + half * 32;
#pragma unroll
    for (int jc = 0; jc < 4; ++jc) {
        ushort8 o8;
#pragma unroll
        for (int j = 0; j < 8; ++j) {
            int t = half * 32 + jc * 8 + j;
            o8[j] = *(const unsigned short*)(T + ((t * 256 + e * 2) ^ ((t & 7) << 4)));
        }
        *(ushort8*)(dst + jc * 8) = o8;
    }
}

// ============================================================================
// Kernel B: flash attention, O^T form, fixed softmax reference (m = 0).
// K: global_load_lds, pre-swizzled source, double-buffered, 1 barrier/tile.
// V: global->reg in TWO ks2-chunks of 8 frags (32 VGPR each) to stay under
//    the 128-VGPR occupancy cliff (r9's 64-VGPR vfrag hit 132 -> Occ halved).
// LDS ops/tile/lane: 46 (r8) -> 22 (Kr16 + Pw4 + Pr2).
// ============================================================================
__global__ __launch_bounds__(256) void flash_kernel(
    const __bf16* __restrict__ Qg, const __bf16* __restrict__ Kg,
    const __bf16* __restrict__ Vtg, const float* __restrict__ mask,
    __bf16* __restrict__ AO)
{
    __shared__ __align__(16) char Kl[2][16384]; // [64 kv][128 e], swz ((kv&7)<<4)
    __shared__ __align__(16) char Pl[8192];     // per-wave [16 q][64 kv], swz ((q&7)<<4)

    const int tid = threadIdx.x;
    const int lane = tid & 63, w = tid >> 6;
    const int l15 = lane & 15, lg = lane >> 4;

    // XCD-aware remap (r8): XCD x owns bh in {4x..4x+3} -> K/V stay in its L2.
    const int wid = blockIdx.y * 32 + blockIdx.x;
    const int xcd = wid & 7, j = wid >> 3;
    const int bh = (xcd << 2) | (j & 3);
    const int q0 = (j >> 2) * 64;
    const int b = bh >> 3;

    // K gload_lds maps: LDS linear dest byte = cidx*16; global source element
    // pre-swizzled so the (kv&7)-XOR read layout comes out right (m173).
    int kgo[4];                 // per-lane global element offset, 4 chunks
#pragma unroll
    for (int it = 0; it < 4; ++it) {
        int cidx = it * 256 + tid;
        int kv = cidx >> 4, c15 = cidx & 15;
        kgo[it] = kv * 128 + ((c15 ^ (kv & 7)) * 8);
    }
    const int ldsb = (w << 6) * 16;  // wave-uniform chunk base within a 4KB slab
    const __bf16* kbase = Kg + (size_t)bh * 2048 * 128;
    const __bf16* vtbase = Vtg + (size_t)bh * 128 * 2048;
    const float* mbase = mask + ((size_t)b * 2048 + q0 + w * 16 + l15) * 2048;
    // per-lane V base: e row l15 (of each 16-row block), kv chunk lg*8
    const __bf16* vlane = vtbase + (size_t)l15 * 2048 + lg * 8;

    bf16x8 qf[4];
    {
        const __bf16* qp = Qg + ((size_t)bh * 2048 + q0 + w * 16 + l15) * 128 + lg * 8;
#pragma unroll
        for (int ks = 0; ks < 4; ++ks) qf[ks] = *(const bf16x8*)(qp + ks * 32);
    }

    f32x4 o_acc[8];                    // O^T: [e-tile ct2][r], col q = l15
#pragma unroll
    for (int i = 0; i < 8; ++i) o_acc[i] = (f32x4){0.f, 0.f, 0.f, 0.f};
    float lacc = 0.f;                  // per-lane partial of row-l15 lsum
    const int pbase = w * 2048 + l15 * 128;
    const int psw = (l15 & 7) << 4;

    // prologue: stage K tile 0 into Kl[0] (async)
#pragma unroll
    for (int it = 0; it < 4; ++it)
        gld16(kbase + kgo[it], Kl[0] + it * 4096 + ldsb);

    int cur = 0;
    for (int kv0 = 0; kv0 < 2048; kv0 += 64) {
        __syncthreads();   // auto vmcnt(0) drains K gload_lds: Kl[cur] ready
        const bool more = (kv0 + 64) < 2048;
        const __bf16* vln = vlane + kv0;

        // V chunk A (ks2 = 0): 8 frags, consumed after QK+softmax (~800 cy)
        bf16x8 vA[8];
#pragma unroll
        for (int ct2 = 0; ct2 < 8; ++ct2)
            vA[ct2] = *(const bf16x8*)(vln + ct2 * 32768);
        // prefetch next K tile into the other buffer (lands by next barrier)
        if (more) {
            const __bf16* kb = kbase + (size_t)(kv0 + 64) * 128;
#pragma unroll
            for (int it = 0; it < 4; ++it)
                gld16(kb + kgo[it], Kl[cur ^ 1] + it * 4096 + ldsb);
        }
        // mask tile for this kv0
        f32x4 mr[4];
#pragma unroll
        for (int ct = 0; ct < 4; ++ct)
            mr[ct] = *(const f32x4*)(mbase + kv0 + ct * 16 + lg * 4);
        __builtin_amdgcn_sched_barrier(0);     // pin all issues before QK

        // S^T = K Q^T : st[ct][r] is (q = l15, kv = ct*16 + lg*4 + r)
        f32x4 st[4];
        __builtin_amdgcn_s_setprio(1);
#pragma unroll
        for (int ct = 0; ct < 4; ++ct) {
            f32x4 acc = (f32x4){0.f, 0.f, 0.f, 0.f};
            const int kvr = ct * 16 + l15;
            const int rowb = kvr * 256, sw = (kvr & 7) << 4;
#pragma unroll
            for (int ks = 0; ks < 4; ++ks) {
                bf16x8 kf = *(const bf16x8*)(Kl[cur] + rowb + ((ks * 64 + lg * 16) ^ sw));
                acc = __builtin_amdgcn_mfma_f32_16x16x32_bf16(kf, qf[ks], acc, 0, 0, 0);
            }
            st[ct] = acc;
        }
        __builtin_amdgcn_s_setprio(0);

        // P = exp(s + mask), fixed reference 0; no cross-lane ops in-loop.
#pragma unroll
        for (int ct = 0; ct < 4; ++ct) {
            union { __bf16 h[4]; unsigned long long u64; } pk;
#pragma unroll
            for (int r = 0; r < 4; ++r) {
                float p = exp2f((st[ct][r] + mr[ct][r]) * LOG2E);
                lacc += p;
                pk.h[r] = (__bf16)p;
            }
            *(unsigned long long*)(Pl + pbase + ((ct * 32 + lg * 8) ^ psw)) = pk.u64;
        }

        // V chunk B (ks2 = 1): issued now, consumed after ks2=0 PV
        bf16x8 vB[8];
#pragma unroll
        for (int ct2 = 0; ct2 < 8; ++ct2)
            vB[ct2] = *(const bf16x8*)(vln + ct2 * 32768 + 32);

        // P write -> P read same-wave ordering (rule #18 fence)
        asm volatile("s_waitcnt lgkmcnt(0)" ::: "memory");
        __builtin_amdgcn_sched_barrier(0);

        // O^T += V^T P^T
        __builtin_amdgcn_s_setprio(1);
        {
            bf16x8 pf0 = *(const bf16x8*)(Pl + pbase + ((lg * 16) ^ psw));
#pragma unroll
            for (int ct2 = 0; ct2 < 8; ++ct2)
                o_acc[ct2] = __builtin_amdgcn_mfma_f32_16x16x32_bf16(vA[ct2], pf0, o_acc[ct2], 0, 0, 0);
            bf16x8 pf1 = *(const bf16x8*)(Pl + pbase + ((64 + lg * 16) ^ psw));
#pragma unroll
            for (int ct2 = 0; ct2 < 8; ++ct2)
                o_acc[ct2] = __builtin_amdgcn_mfma_f32_16x16x32_bf16(vB[ct2], pf1, o_acc[ct2], 0, 0, 0);
        }
        __builtin_amdgcn_s_setprio(0);
        cur ^= 1;
    }

    // epilogue: reduce lsum once (row q=l15 split over 4 lg lanes)
    float tot = lacc;
    tot += __shfl_xor(tot, 16);
    tot += __shfl_xor(tot, 32);
    const float linv = 1.0f / tot;
    const size_t tok = (size_t)b * 2048 + q0 + w * 16 + l15;
    __bf16* aop = AO + tok * 1024 + (bh & 7) * 128;
#pragma unroll
    for (int ct2 = 0; ct2 < 8; ++ct2) {
        union { __bf16 h[4]; unsigned long long u64; } ov;
#pragma unroll
        for (int r = 0; r < 4; ++r) ov.h[r] = (__bf16)(o_acc[ct2][r] * linv);
        *(unsigned long long*)(aop + ct2 * 16 + lg * 4) = ov.u64;
    }
}

// ============================================================================
// Kernel C: output projection. 8 tokens/block, thread = (o = tid>>3, t = tid&7).
// ============================================================================
__global__ __launch_bounds__(128) void outproj_kernel(
    const __bf16* __restrict__ AO, const float* __restrict__ wo,
    const float* __restrict__ bo, float* __restrict__ out)
{
    __shared__ float al[8 * 1032];
    const int tid = threadIdx.x;
    const int t0 = blockIdx.x * 8;
#pragma unroll
    for (int it = 0; it < 8; ++it) {
        bf16x8 v = *(const bf16x8*)(AO + (size_t)(t0 + it) * 1024 + tid * 8);
        f32x4 lo = {(float)v[0], (float)v[1], (float)v[2], (float)v[3]};
        f32x4 hi = {(float)v[4], (float)v[5], (float)v[6], (float)v[7]};
        *(f32x4*)(al + it * 1032 + tid * 8) = lo;
        *(f32x4*)(al + it * 1032 + tid * 8 + 4) = hi;
    }
    __syncthreads();
    const int o = tid >> 3, t = tid & 7;
    float acc[8];
    acc[0] = bo[o];
#pragma unroll
    for (int c = 1; c < 8; ++c) acc[c] = 0.f;
    const float4* w4 = (const float4*)wo + o * 128;
    for (int ii = 0; ii < 128; ++ii) {
        float4 wv = w4[ii];
        f32x4 xlo = *(const f32x4*)(al + t * 1032 + ii * 8);
        f32x4 xhi = *(const f32x4*)(al + t * 1032 + ii * 8 + 4);
        float wr[8] = {wv.x, wv.y, wv.y, wv.y, wv.z, wv.z, wv.z, wv.w};
        float xv[8] = {xlo[0], xlo[1], xlo[2], xlo[3], xhi[0], xhi[1], xhi[2], xhi[3]};
#pragma unroll
        for (int c = 0; c < 8; ++c) acc[c] += xv[c] * wr[c];
    }
    float* op = out + (size_t)(t0 + t) * 128 + o * 8;
    *(float4*)op = (float4){acc[0], acc[1], acc[2], acc[3]};
    *(float4*)(op + 4) = (float4){acc[4], acc[5], acc[6], acc[7]};
}

// ============================================================================
extern "C" void kernel_launch(void* const* d_in, const int* in_sizes, int n_in,
                              void* d_out, int out_size, void* d_ws, size_t ws_size,
                              hipStream_t stream)
{
    const float* x    = (const float*)d_in[0];
    const float* mask = (const float*)d_in[1];
    const float* wq   = (const float*)d_in[2];
    const float* bq   = (const float*)d_in[3];
    const float* wk   = (const float*)d_in[4];
    const float* bk   = (const float*)d_in[5];
    const float* wv   = (const float*)d_in[6];
    const float* bv   = (const float*)d_in[7];
    const float* wo   = (const float*)d_in[8];
    const float* bo   = (const float*)d_in[9];
    float* out = (float*)d_out;

    const size_t SLOT = (size_t)32 * 2048 * 128;  // 8M bf16 elems = 16 MiB
    const size_t need = SLOT * 4 * 2;             // 64 MiB
    if (ws_size < need) {
        hipMemsetAsync(d_out, 0, (size_t)out_size * sizeof(float), stream);
        return;
    }
    __bf16* Qg = (__bf16*)d_ws;
    __bf16* Kg = Qg + SLOT;
    __bf16* Vg = Kg + SLOT;   // V row-major; dead after transv
    __bf16* Vt = Vg + SLOT;
    __bf16* AO = Vg;          // reuse: flash writes AO only after Vg is dead

    proj_kernel<<<TOKS / 4, 128, 0, stream>>>(x, wq, bq, wk, bk, wv, bv, Qg, Kg, Vg);
    transv_kernel<<<dim3(32, 32), 256, 0, stream>>>(Vg, Vt);
    flash_kernel<<<dim3(32, 32), 256, 0, stream>>>(Qg, Kg, Vt, mask, AO);
    outproj_kernel<<<TOKS / 8, 128, 0, stream>>>(AO, wo, bo, out);
}

// Round 11
// 200.973 us; speedup vs baseline: 1.9226x; 1.8238x over previous
//
#include <hip/hip_runtime.h>
#include <hip/hip_bf16.h>

typedef __attribute__((ext_vector_type(8))) __bf16 bf16x8;
typedef __attribute__((ext_vector_type(4))) float f32x4;
typedef __attribute__((ext_vector_type(8))) unsigned short ushort8;

#define TOKS 8192
#define LOG2E 1.4426950408889634f

// ============================================================================
// Kernel A: fused q/k/v per-blade projections.  4 tokens/block, o = tid.
// ============================================================================
__global__ __launch_bounds__(128) void proj_kernel(
    const float* __restrict__ x,
    const float* __restrict__ wq, const float* __restrict__ bq,
    const float* __restrict__ wk, const float* __restrict__ bk,
    const float* __restrict__ wv, const float* __restrict__ bv,
    __bf16* __restrict__ Qg, __bf16* __restrict__ Kg, __bf16* __restrict__ Vg)
{
    __shared__ float xs[512];
    const int tid = threadIdx.x;
    const int t0 = blockIdx.x * 4;
    ((float4*)xs)[tid] = ((const float4*)(x + (size_t)t0 * 128))[tid];
    __syncthreads();
    const int o = tid, h = o >> 4, d = o & 15;

    float acc[3][4][8];
#pragma unroll
    for (int tz = 0; tz < 3; ++tz) {
        const float bias = (tz == 0 ? bq : tz == 1 ? bk : bv)[o];
#pragma unroll
        for (int t = 0; t < 4; ++t) {
            acc[tz][t][0] = bias;
#pragma unroll
            for (int c = 1; c < 8; ++c) acc[tz][t][c] = 0.f;
        }
    }
    const float4* w40 = (const float4*)(wq + o * 64);
    const float4* w41 = (const float4*)(wk + o * 64);
    const float4* w42 = (const float4*)(wv + o * 64);
    for (int i = 0; i < 16; ++i) {
        float4 wv3[3] = {w40[i], w41[i], w42[i]};
#pragma unroll
        for (int t = 0; t < 4; ++t) {
            f32x4 xlo = *(const f32x4*)(xs + t * 128 + i * 8);
            f32x4 xhi = *(const f32x4*)(xs + t * 128 + i * 8 + 4);
            float xv[8] = {xlo[0], xlo[1], xlo[2], xlo[3],
                           xhi[0], xhi[1], xhi[2], xhi[3]};
#pragma unroll
            for (int tz = 0; tz < 3; ++tz) {
                float wr[8] = {wv3[tz].x, wv3[tz].y, wv3[tz].y, wv3[tz].y,
                               wv3[tz].z, wv3[tz].z, wv3[tz].z, wv3[tz].w};
#pragma unroll
                for (int c = 0; c < 8; ++c) acc[tz][t][c] += xv[c] * wr[c];
            }
        }
    }
    const int bb = t0 >> 11, tt0 = t0 & 2047;
    size_t base = (((size_t)(bb * 8 + h)) * 2048 + tt0) * 128 + d * 8;
#pragma unroll
    for (int tz = 0; tz < 3; ++tz) {
        __bf16* Og = tz == 0 ? Qg : tz == 1 ? Kg : Vg;
        const float scale = (tz == 0) ? 0.08838834764831845f : 1.0f;
#pragma unroll
        for (int t = 0; t < 4; ++t) {
            bf16x8 v;
#pragma unroll
            for (int c = 0; c < 8; ++c) v[c] = (__bf16)(acc[tz][t][c] * scale);
            *(bf16x8*)(Og + base + (size_t)t * 128) = v;
        }
    }
}

// ============================================================================
// Kernel A2: V [bh][t][e] -> Vt [bh][e][t] (64-token tiles, LDS swizzled).
// ============================================================================
__global__ __launch_bounds__(256) void transv_kernel(
    const __bf16* __restrict__ Vg, __bf16* __restrict__ Vt)
{
    __shared__ __align__(16) char T[16384];
    const int tid = threadIdx.x;
    const int bh = blockIdx.y, t0 = blockIdx.x * 64;
    const __bf16* src = Vg + ((size_t)bh * 2048 + t0) * 128;
#pragma unroll
    for (int it = 0; it < 4; ++it) {
        int cidx = it * 256 + tid;
        int r = cidx >> 4, e0 = (cidx & 15) * 8;
        bf16x8 v = *(const bf16x8*)(src + r * 128 + e0);
        *(bf16x8*)(T + ((r * 256 + e0 * 2) ^ ((r & 7) << 4))) = v;
    }
    __syncthreads();
    const int e = tid & 127, half = tid >> 7;
    __bf16* dst = Vt + ((size_t)bh * 128 + e) * 2048 + t0 + half * 32;
#pragma unroll
    for (int jc = 0; jc < 4; ++jc) {
        ushort8 o8;
#pragma unroll
        for (int j = 0; j < 8; ++j) {
            int t = half * 32 + jc * 8 + j;
            o8[j] = *(const unsigned short*)(T + ((t * 256 + e * 2) ^ ((t & 7) << 4)));
        }
        *(ushort8*)(dst + jc * 8) = o8;
    }
}

// ============================================================================
// Kernel B: flash attention, O^T form, fixed softmax reference (m = 0),
// P ENTIRELY IN REGISTERS: QK MFMA ct reads K-rows R(ct,m) =
// (ct&1)*32 + (m>>2)*8 + (ct>>1)*4 + (m&3), so lane (l15,lg) directly
// accumulates S^T[kv = ks2*32 + lg*8 + j][q=l15] -> the PV B-fragment is a
// register pack of exp(st), no P LDS round-trip, no lgkm fence.
// K swizzle bits = (kv&3)|((kv>>3)&1)<<2 (== l15&7 on reads under the perm).
// V consumed from LDS (r6/r9/r10 proved V-from-global is VMEM-latency-bound).
// ============================================================================
__global__ __launch_bounds__(256) void flash_kernel(
    const __bf16* __restrict__ Qg, const __bf16* __restrict__ Kg,
    const __bf16* __restrict__ Vtg, const float* __restrict__ mask,
    __bf16* __restrict__ AO)
{
    __shared__ __align__(16) char Kl[16384];   // [64 kv][128 e], swz s(kv)
    __shared__ __align__(16) char Vl[16384];   // [128 e][64 kv], swz ((e&7)<<4)

    const int tid = threadIdx.x;
    const int lane = tid & 63, w = tid >> 6;
    const int l15 = lane & 15, lg = lane >> 4;

    // XCD-aware remap (r8): XCD x owns bh in {4x..4x+3} -> K/V stay in its L2.
    const int wid = blockIdx.y * 32 + blockIdx.x;
    const int xcd = wid & 7, j = wid >> 3;
    const int bh = (xcd << 2) | (j & 3);
    const int q0 = (j >> 2) * 64;
    const int b = bh >> 3;

    int kg[4], klb[4], vg[4], vlb[4];
#pragma unroll
    for (int it = 0; it < 4; ++it) {
        int cidx = it * 256 + tid;
        int kv = cidx >> 4, c15 = cidx & 15;
        int skv = (kv & 3) | (((kv >> 3) & 1) << 2);
        kg[it] = kv * 128 + c15 * 8;
        klb[it] = kv * 256 + ((c15 ^ skv) * 16);
        int e = cidx >> 3, jj = cidx & 7;
        vg[it] = e * 2048 + jj * 8;
        vlb[it] = e * 128 + ((jj * 16) ^ ((e & 7) << 4));
    }
    const __bf16* kbase = Kg + (size_t)bh * 2048 * 128;
    const __bf16* vtbase = Vtg + (size_t)bh * 128 * 2048;
    const float* mbase = mask + ((size_t)b * 2048 + q0 + w * 16 + l15) * 2048;

    bf16x8 qf[4];
    {
        const __bf16* qp = Qg + ((size_t)bh * 2048 + q0 + w * 16 + l15) * 128 + lg * 8;
#pragma unroll
        for (int ks = 0; ks < 4; ++ks) qf[ks] = *(const bf16x8*)(qp + ks * 32);
    }

    f32x4 o_acc[8];                    // O^T: [e-tile ct2][r], col q = l15
#pragma unroll
    for (int i = 0; i < 8; ++i) o_acc[i] = (f32x4){0.f, 0.f, 0.f, 0.f};
    float lacc = 0.f;                  // per-lane partial of row-l15 lsum

    // per-lane K-read bases for the permuted rows (constant over ct via R formula)
    const int ksw = (l15 & 7) << 4;    // s(R(ct,l15)) == l15&7 for all ct

    bf16x8 kreg[4], vreg[4];
#pragma unroll
    for (int it = 0; it < 4; ++it) {
        kreg[it] = *(const bf16x8*)(kbase + kg[it]);
        vreg[it] = *(const bf16x8*)(vtbase + vg[it]);
    }
#pragma unroll
    for (int it = 0; it < 4; ++it) {
        *(bf16x8*)(Kl + klb[it]) = kreg[it];
        *(bf16x8*)(Vl + vlb[it]) = vreg[it];
    }
    f32x4 mr[4];
#pragma unroll
    for (int ct = 0; ct < 4; ++ct)
        mr[ct] = *(const f32x4*)(mbase + (ct & 1) * 32 + lg * 8 + ((ct >> 1) << 2));

    for (int kv0 = 0; kv0 < 2048; kv0 += 64) {
        __syncthreads();                       // barA: tile kv0 visible in LDS
        const bool more = (kv0 + 64) < 2048;
        if (more) {                            // next-tile loads fly under compute
            const __bf16* kb = kbase + (size_t)(kv0 + 64) * 128;
            const __bf16* vb = vtbase + (kv0 + 64);
#pragma unroll
            for (int it = 0; it < 4; ++it) {
                kreg[it] = *(const bf16x8*)(kb + kg[it]);
                vreg[it] = *(const bf16x8*)(vb + vg[it]);
            }
        }

        // S^T = K Q^T over permuted rows: st[ct][r] = S[q=l15][kv=(ct&1)*32+lg*8+(ct>>1)*4+r]
        f32x4 st[4];
        __builtin_amdgcn_s_setprio(1);
#pragma unroll
        for (int ct = 0; ct < 4; ++ct) {
            f32x4 acc = (f32x4){0.f, 0.f, 0.f, 0.f};
            const int R = (ct & 1) * 32 + ((l15 >> 2) << 3) + ((ct >> 1) << 2) + (l15 & 3);
            const int rowb = R * 256;
#pragma unroll
            for (int ks = 0; ks < 4; ++ks) {
                bf16x8 kf = *(const bf16x8*)(Kl + rowb + ((ks * 64 + lg * 16) ^ ksw));
                acc = __builtin_amdgcn_mfma_f32_16x16x32_bf16(kf, qf[ks], acc, 0, 0, 0);
            }
            st[ct] = acc;
        }
        __builtin_amdgcn_s_setprio(0);

        // P = exp(s + mask) (fixed ref 0), packed straight into PV B-fragments:
        // pf[ks2].h[j] = p[ct = ks2 + 2*(j>>2)][r = j&3]
        union { __bf16 h[8]; bf16x8 v; } pk0, pk1;
#pragma unroll
        for (int ct = 0; ct < 4; ++ct) {
#pragma unroll
            for (int r = 0; r < 4; ++r) {
                float p = exp2f((st[ct][r] + mr[ct][r]) * LOG2E);
                lacc += p;
                const int jj = ((ct >> 1) << 2) + r;
                if (ct & 1) pk1.h[jj] = (__bf16)p;
                else        pk0.h[jj] = (__bf16)p;
            }
        }

        // O^T += V^T P^T (P from registers, V from LDS)
        __builtin_amdgcn_s_setprio(1);
#pragma unroll
        for (int ks2 = 0; ks2 < 2; ++ks2) {
            bf16x8 pf = ks2 ? pk1.v : pk0.v;
#pragma unroll
            for (int ct2 = 0; ct2 < 8; ++ct2) {
                const int e = ct2 * 16 + l15;
                bf16x8 vf = *(const bf16x8*)(Vl + e * 128 +
                                             ((ks2 * 64 + lg * 16) ^ ((e & 7) << 4)));
                o_acc[ct2] = __builtin_amdgcn_mfma_f32_16x16x32_bf16(vf, pf, o_acc[ct2], 0, 0, 0);
            }
        }
        __builtin_amdgcn_s_setprio(0);
        __syncthreads();                       // barC: all reads of Kl/Vl done

        if (more) {                            // stage next tile + next mask
#pragma unroll
            for (int it = 0; it < 4; ++it) {
                *(bf16x8*)(Kl + klb[it]) = kreg[it];
                *(bf16x8*)(Vl + vlb[it]) = vreg[it];
            }
#pragma unroll
            for (int ct = 0; ct < 4; ++ct)
                mr[ct] = *(const f32x4*)(mbase + kv0 + 64 +
                                         (ct & 1) * 32 + lg * 8 + ((ct >> 1) << 2));
        }
    }

    // epilogue: reduce lsum once (row q=l15 split over 4 lg lanes)
    float tot = lacc;
    tot += __shfl_xor(tot, 16);
    tot += __shfl_xor(tot, 32);
    const float linv = 1.0f / tot;
    const size_t tok = (size_t)b * 2048 + q0 + w * 16 + l15;
    __bf16* aop = AO + tok * 1024 + (bh & 7) * 128;
#pragma unroll
    for (int ct2 = 0; ct2 < 8; ++ct2) {
        union { __bf16 h[4]; unsigned long long u64; } ov;
#pragma unroll
        for (int r = 0; r < 4; ++r) ov.h[r] = (__bf16)(o_acc[ct2][r] * linv);
        *(unsigned long long*)(aop + ct2 * 16 + lg * 4) = ov.u64;
    }
}

// ============================================================================
// Kernel C: output projection. 8 tokens/block, thread = (o = tid>>3, t = tid&7).
// ============================================================================
__global__ __launch_bounds__(128) void outproj_kernel(
    const __bf16* __restrict__ AO, const float* __restrict__ wo,
    const float* __restrict__ bo, float* __restrict__ out)
{
    __shared__ float al[8 * 1032];
    const int tid = threadIdx.x;
    const int t0 = blockIdx.x * 8;
#pragma unroll
    for (int it = 0; it < 8; ++it) {
        bf16x8 v = *(const bf16x8*)(AO + (size_t)(t0 + it) * 1024 + tid * 8);
        f32x4 lo = {(float)v[0], (float)v[1], (float)v[2], (float)v[3]};
        f32x4 hi = {(float)v[4], (float)v[5], (float)v[6], (float)v[7]};
        *(f32x4*)(al + it * 1032 + tid * 8) = lo;
        *(f32x4*)(al + it * 1032 + tid * 8 + 4) = hi;
    }
    __syncthreads();
    const int o = tid >> 3, t = tid & 7;
    float acc[8];
    acc[0] = bo[o];
#pragma unroll
    for (int c = 1; c < 8; ++c) acc[c] = 0.f;
    const float4* w4 = (const float4*)wo + o * 128;
    for (int ii = 0; ii < 128; ++ii) {
        float4 wv = w4[ii];
        f32x4 xlo = *(const f32x4*)(al + t * 1032 + ii * 8);
        f32x4 xhi = *(const f32x4*)(al + t * 1032 + ii * 8 + 4);
        float wr[8] = {wv.x, wv.y, wv.y, wv.y, wv.z, wv.z, wv.z, wv.w};
        float xv[8] = {xlo[0], xlo[1], xlo[2], xlo[3], xhi[0], xhi[1], xhi[2], xhi[3]};
#pragma unroll
        for (int c = 0; c < 8; ++c) acc[c] += xv[c] * wr[c];
    }
    float* op = out + (size_t)(t0 + t) * 128 + o * 8;
    *(float4*)op = (float4){acc[0], acc[1], acc[2], acc[3]};
    *(float4*)(op + 4) = (float4){acc[4], acc[5], acc[6], acc[7]};
}

// ============================================================================
extern "C" void kernel_launch(void* const* d_in, const int* in_sizes, int n_in,
                              void* d_out, int out_size, void* d_ws, size_t ws_size,
                              hipStream_t stream)
{
    const float* x    = (const float*)d_in[0];
    const float* mask = (const float*)d_in[1];
    const float* wq   = (const float*)d_in[2];
    const float* bq   = (const float*)d_in[3];
    const float* wk   = (const float*)d_in[4];
    const float* bk   = (const float*)d_in[5];
    const float* wv   = (const float*)d_in[6];
    const float* bv   = (const float*)d_in[7];
    const float* wo   = (const float*)d_in[8];
    const float* bo   = (const float*)d_in[9];
    float* out = (float*)d_out;

    const size_t SLOT = (size_t)32 * 2048 * 128;  // 8M bf16 elems = 16 MiB
    const size_t need = SLOT * 4 * 2;             // 64 MiB
    if (ws_size < need) {
        hipMemsetAsync(d_out, 0, (size_t)out_size * sizeof(float), stream);
        return;
    }
    __bf16* Qg = (__bf16*)d_ws;
    __bf16* Kg = Qg + SLOT;
    __bf16* Vg = Kg + SLOT;   // V row-major; dead after transv
    __bf16* Vt = Vg + SLOT;
    __bf16* AO = Vg;          // reuse: flash writes AO only after Vg is dead

    proj_kernel<<<TOKS / 4, 128, 0, stream>>>(x, wq, bq, wk, bk, wv, bv, Qg, Kg, Vg);
    transv_kernel<<<dim3(32, 32), 256, 0, stream>>>(Vg, Vt);
    flash_kernel<<<dim3(32, 32), 256, 0, stream>>>(Qg, Kg, Vt, mask, AO);
    outproj_kernel<<<TOKS / 8, 128, 0, stream>>>(AO, wo, bo, out);
}

// Round 12
// 195.407 us; speedup vs baseline: 1.9773x; 1.0285x over previous
//
#include <hip/hip_runtime.h>
#include <hip/hip_bf16.h>

typedef __attribute__((ext_vector_type(8))) __bf16 bf16x8;
typedef __attribute__((ext_vector_type(4))) float f32x4;
typedef __attribute__((ext_vector_type(8))) unsigned short ushort8;

#define TOKS 8192
#define LOG2E 1.4426950408889634f

// ============================================================================
// Kernel A: fused q/k/v per-blade projections.  4 tokens/block, o = tid.
// Q pre-scaled by LOG2E/sqrt(128) so flash's exp2 needs no multiply.
// ============================================================================
__global__ __launch_bounds__(128) void proj_kernel(
    const float* __restrict__ x,
    const float* __restrict__ wq, const float* __restrict__ bq,
    const float* __restrict__ wk, const float* __restrict__ bk,
    const float* __restrict__ wv, const float* __restrict__ bv,
    __bf16* __restrict__ Qg, __bf16* __restrict__ Kg, __bf16* __restrict__ Vg)
{
    __shared__ float xs[512];
    const int tid = threadIdx.x;
    const int t0 = blockIdx.x * 4;
    ((float4*)xs)[tid] = ((const float4*)(x + (size_t)t0 * 128))[tid];
    __syncthreads();
    const int o = tid, h = o >> 4, d = o & 15;

    float acc[3][4][8];
#pragma unroll
    for (int tz = 0; tz < 3; ++tz) {
        const float bias = (tz == 0 ? bq : tz == 1 ? bk : bv)[o];
#pragma unroll
        for (int t = 0; t < 4; ++t) {
            acc[tz][t][0] = bias;
#pragma unroll
            for (int c = 1; c < 8; ++c) acc[tz][t][c] = 0.f;
        }
    }
    const float4* w40 = (const float4*)(wq + o * 64);
    const float4* w41 = (const float4*)(wk + o * 64);
    const float4* w42 = (const float4*)(wv + o * 64);
    for (int i = 0; i < 16; ++i) {
        float4 wv3[3] = {w40[i], w41[i], w42[i]};
#pragma unroll
        for (int t = 0; t < 4; ++t) {
            f32x4 xlo = *(const f32x4*)(xs + t * 128 + i * 8);
            f32x4 xhi = *(const f32x4*)(xs + t * 128 + i * 8 + 4);
            float xv[8] = {xlo[0], xlo[1], xlo[2], xlo[3],
                           xhi[0], xhi[1], xhi[2], xhi[3]};
#pragma unroll
            for (int tz = 0; tz < 3; ++tz) {
                float wr[8] = {wv3[tz].x, wv3[tz].y, wv3[tz].y, wv3[tz].y,
                               wv3[tz].z, wv3[tz].z, wv3[tz].z, wv3[tz].w};
#pragma unroll
                for (int c = 0; c < 8; ++c) acc[tz][t][c] += xv[c] * wr[c];
            }
        }
    }
    const int bb = t0 >> 11, tt0 = t0 & 2047;
    size_t base = (((size_t)(bb * 8 + h)) * 2048 + tt0) * 128 + d * 8;
#pragma unroll
    for (int tz = 0; tz < 3; ++tz) {
        __bf16* Og = tz == 0 ? Qg : tz == 1 ? Kg : Vg;
        const float scale = (tz == 0) ? (0.08838834764831845f * LOG2E) : 1.0f;
#pragma unroll
        for (int t = 0; t < 4; ++t) {
            bf16x8 v;
#pragma unroll
            for (int c = 0; c < 8; ++c) v[c] = (__bf16)(acc[tz][t][c] * scale);
            *(bf16x8*)(Og + base + (size_t)t * 128) = v;
        }
    }
}

// ============================================================================
// Kernel A2: V [bh][t][e] -> Vt [bh][e][t] (64-token tiles, LDS swizzled).
// ============================================================================
__global__ __launch_bounds__(256) void transv_kernel(
    const __bf16* __restrict__ Vg, __bf16* __restrict__ Vt)
{
    __shared__ __align__(16) char T[16384];
    const int tid = threadIdx.x;
    const int bh = blockIdx.y, t0 = blockIdx.x * 64;
    const __bf16* src = Vg + ((size_t)bh * 2048 + t0) * 128;
#pragma unroll
    for (int it = 0; it < 4; ++it) {
        int cidx = it * 256 + tid;
        int r = cidx >> 4, e0 = (cidx & 15) * 8;
        bf16x8 v = *(const bf16x8*)(src + r * 128 + e0);
        *(bf16x8*)(T + ((r * 256 + e0 * 2) ^ ((r & 7) << 4))) = v;
    }
    __syncthreads();
    const int e = tid & 127, half = tid >> 7;
    __bf16* dst = Vt + ((size_t)bh * 128 + e) * 2048 + t0 + half * 32;
#pragma unroll
    for (int jc = 0; jc < 4; ++jc) {
        ushort8 o8;
#pragma unroll
        for (int j = 0; j < 8; ++j) {
            int t = half * 32 + jc * 8 + j;
            o8[j] = *(const unsigned short*)(T + ((t * 256 + e * 2) ^ ((t & 7) << 4)));
        }
        *(ushort8*)(dst + jc * 8) = o8;
    }
}

// ============================================================================
// Kernel B: flash attention, O^T form, fixed softmax ref (m=0), P in regs
// (r11 permuted-K-row trick). New in r12:
//  - mask (x LOG2E) enters as the QK MFMA C-initializer (off critical path)
//  - Q carries LOG2E -> p = exp2f(st) bare
//  - exp/PV interleaved: pk0 -> PV(ks2=0) -> pk1 -> PV(ks2=1)
//  - lsum in a 4-chain f32x4 accumulator
// ============================================================================
__global__ __launch_bounds__(256) void flash_kernel(
    const __bf16* __restrict__ Qg, const __bf16* __restrict__ Kg,
    const __bf16* __restrict__ Vtg, const float* __restrict__ mask,
    __bf16* __restrict__ AO)
{
    __shared__ __align__(16) char Kl[16384];   // [64 kv][128 e], swz s(kv)
    __shared__ __align__(16) char Vl[16384];   // [128 e][64 kv], swz ((e&7)<<4)

    const int tid = threadIdx.x;
    const int lane = tid & 63, w = tid >> 6;
    const int l15 = lane & 15, lg = lane >> 4;

    // XCD-aware remap (r8): XCD x owns bh in {4x..4x+3} -> K/V stay in its L2.
    const int wid = blockIdx.y * 32 + blockIdx.x;
    const int xcd = wid & 7, j = wid >> 3;
    const int bh = (xcd << 2) | (j & 3);
    const int q0 = (j >> 2) * 64;
    const int b = bh >> 3;

    int kg[4], klb[4], vg[4], vlb[4];
#pragma unroll
    for (int it = 0; it < 4; ++it) {
        int cidx = it * 256 + tid;
        int kv = cidx >> 4, c15 = cidx & 15;
        int skv = (kv & 3) | (((kv >> 3) & 1) << 2);
        kg[it] = kv * 128 + c15 * 8;
        klb[it] = kv * 256 + ((c15 ^ skv) * 16);
        int e = cidx >> 3, jj = cidx & 7;
        vg[it] = e * 2048 + jj * 8;
        vlb[it] = e * 128 + ((jj * 16) ^ ((e & 7) << 4));
    }
    const __bf16* kbase = Kg + (size_t)bh * 2048 * 128;
    const __bf16* vtbase = Vtg + (size_t)bh * 128 * 2048;
    const float* mbase = mask + ((size_t)b * 2048 + q0 + w * 16 + l15) * 2048;

    bf16x8 qf[4];
    {
        const __bf16* qp = Qg + ((size_t)bh * 2048 + q0 + w * 16 + l15) * 128 + lg * 8;
#pragma unroll
        for (int ks = 0; ks < 4; ++ks) qf[ks] = *(const bf16x8*)(qp + ks * 32);
    }

    f32x4 o_acc[8];                    // O^T: [e-tile ct2][r], col q = l15
#pragma unroll
    for (int i = 0; i < 8; ++i) o_acc[i] = (f32x4){0.f, 0.f, 0.f, 0.f};
    f32x4 lacc4 = (f32x4){0.f, 0.f, 0.f, 0.f};  // 4 independent lsum chains

    const int ksw = (l15 & 7) << 4;    // s(R(ct,l15)) == l15&7 for all ct

    bf16x8 kreg[4], vreg[4];
#pragma unroll
    for (int it = 0; it < 4; ++it) {
        kreg[it] = *(const bf16x8*)(kbase + kg[it]);
        vreg[it] = *(const bf16x8*)(vtbase + vg[it]);
    }
#pragma unroll
    for (int it = 0; it < 4; ++it) {
        *(bf16x8*)(Kl + klb[it]) = kreg[it];
        *(bf16x8*)(Vl + vlb[it]) = vreg[it];
    }
    f32x4 mr[4];
#pragma unroll
    for (int ct = 0; ct < 4; ++ct) {
        f32x4 mv = *(const f32x4*)(mbase + (ct & 1) * 32 + lg * 8 + ((ct >> 1) << 2));
#pragma unroll
        for (int r = 0; r < 4; ++r) mr[ct][r] = mv[r] * LOG2E;
    }

    for (int kv0 = 0; kv0 < 2048; kv0 += 64) {
        __syncthreads();                       // barA: tile kv0 visible in LDS
        const bool more = (kv0 + 64) < 2048;
        if (more) {                            // next-tile loads fly under compute
            const __bf16* kb = kbase + (size_t)(kv0 + 64) * 128;
            const __bf16* vb = vtbase + (kv0 + 64);
#pragma unroll
            for (int it = 0; it < 4; ++it) {
                kreg[it] = *(const bf16x8*)(kb + kg[it]);
                vreg[it] = *(const bf16x8*)(vb + vg[it]);
            }
        }

        // S^T(log2-units) = K Q^T + mask*LOG2E (as C-init), permuted rows:
        // st[ct][r] for kv = (ct&1)*32 + lg*8 + (ct>>1)*4 + r, q = l15
        f32x4 st[4];
        __builtin_amdgcn_s_setprio(1);
#pragma unroll
        for (int ct = 0; ct < 4; ++ct) {
            f32x4 acc = mr[ct];
            const int R = (ct & 1) * 32 + ((l15 >> 2) << 3) + ((ct >> 1) << 2) + (l15 & 3);
            const int rowb = R * 256;
#pragma unroll
            for (int ks = 0; ks < 4; ++ks) {
                bf16x8 kf = *(const bf16x8*)(Kl + rowb + ((ks * 64 + lg * 16) ^ ksw));
                acc = __builtin_amdgcn_mfma_f32_16x16x32_bf16(kf, qf[ks], acc, 0, 0, 0);
            }
            st[ct] = acc;
        }
        __builtin_amdgcn_s_setprio(0);

        // pk0 (ct 0,2) -> PV ks2=0; pk1 (ct 1,3) issues under PV-0's shadow.
        union { __bf16 h[8]; bf16x8 v; } pk0, pk1;
#pragma unroll
        for (int ct = 0; ct < 4; ct += 2) {    // ct = 0, 2
#pragma unroll
            for (int r = 0; r < 4; ++r) {
                float p = exp2f(st[ct][r]);
                lacc4[r] += p;
                pk0.h[((ct >> 1) << 2) + r] = (__bf16)p;
            }
        }
        __builtin_amdgcn_s_setprio(1);
#pragma unroll
        for (int ct2 = 0; ct2 < 8; ++ct2) {
            const int e = ct2 * 16 + l15;
            bf16x8 vf = *(const bf16x8*)(Vl + e * 128 + ((lg * 16) ^ ((e & 7) << 4)));
            o_acc[ct2] = __builtin_amdgcn_mfma_f32_16x16x32_bf16(vf, pk0.v, o_acc[ct2], 0, 0, 0);
        }
        __builtin_amdgcn_s_setprio(0);
#pragma unroll
        for (int ct = 1; ct < 4; ct += 2) {    // ct = 1, 3
#pragma unroll
            for (int r = 0; r < 4; ++r) {
                float p = exp2f(st[ct][r]);
                lacc4[r] += p;
                pk1.h[((ct >> 1) << 2) + r] = (__bf16)p;
            }
        }
        __builtin_amdgcn_s_setprio(1);
#pragma unroll
        for (int ct2 = 0; ct2 < 8; ++ct2) {
            const int e = ct2 * 16 + l15;
            bf16x8 vf = *(const bf16x8*)(Vl + e * 128 + ((64 + lg * 16) ^ ((e & 7) << 4)));
            o_acc[ct2] = __builtin_amdgcn_mfma_f32_16x16x32_bf16(vf, pk1.v, o_acc[ct2], 0, 0, 0);
        }
        __builtin_amdgcn_s_setprio(0);
        __syncthreads();                       // barC: all reads of Kl/Vl done

        if (more) {                            // stage next tile + next mask
#pragma unroll
            for (int it = 0; it < 4; ++it) {
                *(bf16x8*)(Kl + klb[it]) = kreg[it];
                *(bf16x8*)(Vl + vlb[it]) = vreg[it];
            }
#pragma unroll
            for (int ct = 0; ct < 4; ++ct) {
                f32x4 mv = *(const f32x4*)(mbase + kv0 + 64 +
                                           (ct & 1) * 32 + lg * 8 + ((ct >> 1) << 2));
#pragma unroll
                for (int r = 0; r < 4; ++r) mr[ct][r] = mv[r] * LOG2E;
            }
        }
    }

    // epilogue: fold 4 chains, then reduce across lg lanes (2 shuffles)
    float tot = (lacc4[0] + lacc4[1]) + (lacc4[2] + lacc4[3]);
    tot += __shfl_xor(tot, 16);
    tot += __shfl_xor(tot, 32);
    const float linv = 1.0f / tot;
    const size_t tok = (size_t)b * 2048 + q0 + w * 16 + l15;
    __bf16* aop = AO + tok * 1024 + (bh & 7) * 128;
#pragma unroll
    for (int ct2 = 0; ct2 < 8; ++ct2) {
        union { __bf16 h[4]; unsigned long long u64; } ov;
#pragma unroll
        for (int r = 0; r < 4; ++r) ov.h[r] = (__bf16)(o_acc[ct2][r] * linv);
        *(unsigned long long*)(aop + ct2 * 16 + lg * 4) = ov.u64;
    }
}

// ============================================================================
// Kernel C: output projection. 8 tokens/block, thread = (o = tid>>3, t = tid&7).
// ============================================================================
__global__ __launch_bounds__(128) void outproj_kernel(
    const __bf16* __restrict__ AO, const float* __restrict__ wo,
    const float* __restrict__ bo, float* __restrict__ out)
{
    __shared__ float al[8 * 1032];
    const int tid = threadIdx.x;
    const int t0 = blockIdx.x * 8;
#pragma unroll
    for (int it = 0; it < 8; ++it) {
        bf16x8 v = *(const bf16x8*)(AO + (size_t)(t0 + it) * 1024 + tid * 8);
        f32x4 lo = {(float)v[0], (float)v[1], (float)v[2], (float)v[3]};
        f32x4 hi = {(float)v[4], (float)v[5], (float)v[6], (float)v[7]};
        *(f32x4*)(al + it * 1032 + tid * 8) = lo;
        *(f32x4*)(al + it * 1032 + tid * 8 + 4) = hi;
    }
    __syncthreads();
    const int o = tid >> 3, t = tid & 7;
    float acc[8];
    acc[0] = bo[o];
#pragma unroll
    for (int c = 1; c < 8; ++c) acc[c] = 0.f;
    const float4* w4 = (const float4*)wo + o * 128;
    for (int ii = 0; ii < 128; ++ii) {
        float4 wv = w4[ii];
        f32x4 xlo = *(const f32x4*)(al + t * 1032 + ii * 8);
        f32x4 xhi = *(const f32x4*)(al + t * 1032 + ii * 8 + 4);
        float wr[8] = {wv.x, wv.y, wv.y, wv.y, wv.z, wv.z, wv.z, wv.w};
        float xv[8] = {xlo[0], xlo[1], xlo[2], xlo[3], xhi[0], xhi[1], xhi[2], xhi[3]};
#pragma unroll
        for (int c = 0; c < 8; ++c) acc[c] += xv[c] * wr[c];
    }
    float* op = out + (size_t)(t0 + t) * 128 + o * 8;
    *(float4*)op = (float4){acc[0], acc[1], acc[2], acc[3]};
    *(float4*)(op + 4) = (float4){acc[4], acc[5], acc[6], acc[7]};
}

// ============================================================================
extern "C" void kernel_launch(void* const* d_in, const int* in_sizes, int n_in,
                              void* d_out, int out_size, void* d_ws, size_t ws_size,
                              hipStream_t stream)
{
    const float* x    = (const float*)d_in[0];
    const float* mask = (const float*)d_in[1];
    const float* wq   = (const float*)d_in[2];
    const float* bq   = (const float*)d_in[3];
    const float* wk   = (const float*)d_in[4];
    const float* bk   = (const float*)d_in[5];
    const float* wv   = (const float*)d_in[6];
    const float* bv   = (const float*)d_in[7];
    const float* wo   = (const float*)d_in[8];
    const float* bo   = (const float*)d_in[9];
    float* out = (float*)d_out;

    const size_t SLOT = (size_t)32 * 2048 * 128;  // 8M bf16 elems = 16 MiB
    const size_t need = SLOT * 4 * 2;             // 64 MiB
    if (ws_size < need) {
        hipMemsetAsync(d_out, 0, (size_t)out_size * sizeof(float), stream);
        return;
    }
    __bf16* Qg = (__bf16*)d_ws;
    __bf16* Kg = Qg + SLOT;
    __bf16* Vg = Kg + SLOT;   // V row-major; dead after transv
    __bf16* Vt = Vg + SLOT;
    __bf16* AO = Vg;          // reuse: flash writes AO only after Vg is dead

    proj_kernel<<<TOKS / 4, 128, 0, stream>>>(x, wq, bq, wk, bk, wv, bv, Qg, Kg, Vg);
    transv_kernel<<<dim3(32, 32), 256, 0, stream>>>(Vg, Vt);
    flash_kernel<<<dim3(32, 32), 256, 0, stream>>>(Qg, Kg, Vt, mask, AO);
    outproj_kernel<<<TOKS / 8, 128, 0, stream>>>(AO, wo, bo, out);
}

// Round 13
// 188.628 us; speedup vs baseline: 2.0484x; 1.0359x over previous
//
#include <hip/hip_runtime.h>
#include <hip/hip_bf16.h>

typedef __attribute__((ext_vector_type(8))) __bf16 bf16x8;
typedef __attribute__((ext_vector_type(4))) float f32x4;
typedef __attribute__((ext_vector_type(8))) unsigned short ushort8;

#define TOKS 8192
#define LOG2E 1.4426950408889634f

// ============================================================================
// Kernel A: fused q/k/v per-blade projections.  4 tokens/block, o = tid.
// Q pre-scaled by LOG2E/sqrt(128) so flash's exp2 needs no multiply.
// ============================================================================
__global__ __launch_bounds__(128) void proj_kernel(
    const float* __restrict__ x,
    const float* __restrict__ wq, const float* __restrict__ bq,
    const float* __restrict__ wk, const float* __restrict__ bk,
    const float* __restrict__ wv, const float* __restrict__ bv,
    __bf16* __restrict__ Qg, __bf16* __restrict__ Kg, __bf16* __restrict__ Vg)
{
    __shared__ float xs[512];
    const int tid = threadIdx.x;
    const int t0 = blockIdx.x * 4;
    ((float4*)xs)[tid] = ((const float4*)(x + (size_t)t0 * 128))[tid];
    __syncthreads();
    const int o = tid, h = o >> 4, d = o & 15;

    float acc[3][4][8];
#pragma unroll
    for (int tz = 0; tz < 3; ++tz) {
        const float bias = (tz == 0 ? bq : tz == 1 ? bk : bv)[o];
#pragma unroll
        for (int t = 0; t < 4; ++t) {
            acc[tz][t][0] = bias;
#pragma unroll
            for (int c = 1; c < 8; ++c) acc[tz][t][c] = 0.f;
        }
    }
    const float4* w40 = (const float4*)(wq + o * 64);
    const float4* w41 = (const float4*)(wk + o * 64);
    const float4* w42 = (const float4*)(wv + o * 64);
    for (int i = 0; i < 16; ++i) {
        float4 wv3[3] = {w40[i], w41[i], w42[i]};
#pragma unroll
        for (int t = 0; t < 4; ++t) {
            f32x4 xlo = *(const f32x4*)(xs + t * 128 + i * 8);
            f32x4 xhi = *(const f32x4*)(xs + t * 128 + i * 8 + 4);
            float xv[8] = {xlo[0], xlo[1], xlo[2], xlo[3],
                           xhi[0], xhi[1], xhi[2], xhi[3]};
#pragma unroll
            for (int tz = 0; tz < 3; ++tz) {
                float wr[8] = {wv3[tz].x, wv3[tz].y, wv3[tz].y, wv3[tz].y,
                               wv3[tz].z, wv3[tz].z, wv3[tz].z, wv3[tz].w};
#pragma unroll
                for (int c = 0; c < 8; ++c) acc[tz][t][c] += xv[c] * wr[c];
            }
        }
    }
    const int bb = t0 >> 11, tt0 = t0 & 2047;
    size_t base = (((size_t)(bb * 8 + h)) * 2048 + tt0) * 128 + d * 8;
#pragma unroll
    for (int tz = 0; tz < 3; ++tz) {
        __bf16* Og = tz == 0 ? Qg : tz == 1 ? Kg : Vg;
        const float scale = (tz == 0) ? (0.08838834764831845f * LOG2E) : 1.0f;
#pragma unroll
        for (int t = 0; t < 4; ++t) {
            bf16x8 v;
#pragma unroll
            for (int c = 0; c < 8; ++c) v[c] = (__bf16)(acc[tz][t][c] * scale);
            *(bf16x8*)(Og + base + (size_t)t * 128) = v;
        }
    }
}

// ============================================================================
// Kernel A2: V [bh][t][e] -> Vt [bh][e][t] (64-token tiles, LDS swizzled).
// ============================================================================
__global__ __launch_bounds__(256) void transv_kernel(
    const __bf16* __restrict__ Vg, __bf16* __restrict__ Vt)
{
    __shared__ __align__(16) char T[16384];
    const int tid = threadIdx.x;
    const int bh = blockIdx.y, t0 = blockIdx.x * 64;
    const __bf16* src = Vg + ((size_t)bh * 2048 + t0) * 128;
#pragma unroll
    for (int it = 0; it < 4; ++it) {
        int cidx = it * 256 + tid;
        int r = cidx >> 4, e0 = (cidx & 15) * 8;
        bf16x8 v = *(const bf16x8*)(src + r * 128 + e0);
        *(bf16x8*)(T + ((r * 256 + e0 * 2) ^ ((r & 7) << 4))) = v;
    }
    __syncthreads();
    const int e = tid & 127, half = tid >> 7;
    __bf16* dst = Vt + ((size_t)bh * 128 + e) * 2048 + t0 + half * 32;
#pragma unroll
    for (int jc = 0; jc < 4; ++jc) {
        ushort8 o8;
#pragma unroll
        for (int j = 0; j < 8; ++j) {
            int t = half * 32 + jc * 8 + j;
            o8[j] = *(const unsigned short*)(T + ((t * 256 + e * 2) ^ ((t & 7) << 4)));
        }
        *(ushort8*)(dst + jc * 8) = o8;
    }
}

// ============================================================================
// Kernel B: flash attention (r12 structure) + HOISTED LDS addressing:
// all 32 LDS read addresses are loop-invariant -> 6 base pointers + compile
// time immediates; global staging & mask via running pointers. Goal: delete
// the ~150 addr-VALU ops/tile that made VALUBusy 42%.
// ============================================================================
__global__ __launch_bounds__(256) void flash_kernel(
    const __bf16* __restrict__ Qg, const __bf16* __restrict__ Kg,
    const __bf16* __restrict__ Vtg, const float* __restrict__ mask,
    __bf16* __restrict__ AO)
{
    __shared__ __align__(16) char Kl[16384];   // [64 kv][128 e], swz s(kv)
    __shared__ __align__(16) char Vl[16384];   // [128 e][64 kv], swz ((e&7)<<4)

    const int tid = threadIdx.x;
    const int lane = tid & 63, w = tid >> 6;
    const int l15 = lane & 15, lg = lane >> 4;

    // XCD-aware remap (r8): XCD x owns bh in {4x..4x+3} -> K/V stay in its L2.
    const int wid = blockIdx.y * 32 + blockIdx.x;
    const int xcd = wid & 7, j = wid >> 3;
    const int bh = (xcd << 2) | (j & 3);
    const int q0 = (j >> 2) * 64;
    const int b = bh >> 3;

    int kg[4], klb[4], vg[4], vlb[4];
#pragma unroll
    for (int it = 0; it < 4; ++it) {
        int cidx = it * 256 + tid;
        int kv = cidx >> 4, c15 = cidx & 15;
        int skv = (kv & 3) | (((kv >> 3) & 1) << 2);
        kg[it] = kv * 128 + c15 * 8;
        klb[it] = kv * 256 + ((c15 ^ skv) * 16);
        int e = cidx >> 3, jj = cidx & 7;
        vg[it] = e * 2048 + jj * 8;
        vlb[it] = e * 128 + ((jj * 16) ^ ((e & 7) << 4));
    }
    const __bf16* kbase = Kg + (size_t)bh * 2048 * 128;
    const __bf16* vtbase = Vtg + (size_t)bh * 128 * 2048;
    const float* mbase = mask + ((size_t)b * 2048 + q0 + w * 16 + l15) * 2048;

    bf16x8 qf[4];
    {
        const __bf16* qp = Qg + ((size_t)bh * 2048 + q0 + w * 16 + l15) * 128 + lg * 8;
#pragma unroll
        for (int ks = 0; ks < 4; ++ks) qf[ks] = *(const bf16x8*)(qp + ks * 32);
    }

    f32x4 o_acc[8];                    // O^T: [e-tile ct2][r], col q = l15
#pragma unroll
    for (int i = 0; i < 8; ++i) o_acc[i] = (f32x4){0.f, 0.f, 0.f, 0.f};
    f32x4 lacc4 = (f32x4){0.f, 0.f, 0.f, 0.f};

    // ---- hoisted loop-invariant LDS read base pointers ----
    const int ksw = (l15 & 7) << 4;    // s(R(ct,l15)) == l15&7 for all ct
    const int kb15 = (((l15 >> 2) << 3) + (l15 & 3)) * 256;
    const char* krd0 = Kl + kb15 + ((lg * 16) ^ ksw);          // ks=0
    const char* krd1 = Kl + kb15 + ((64 + lg * 16) ^ ksw);     // ks=1
    const char* krd2 = Kl + kb15 + ((128 + lg * 16) ^ ksw);    // ks=2
    const char* krd3 = Kl + kb15 + ((192 + lg * 16) ^ ksw);    // ks=3
    const char* vrd0 = Vl + l15 * 128 + ((lg * 16) ^ ksw);     // ks2=0
    const char* vrd1 = Vl + l15 * 128 + ((64 + lg * 16) ^ ksw);// ks2=1
    // K read: krd{ks} + (ct&1)*8192 + (ct>>1)*1024  (compile-time immediates)
    // V read: vrd{ks2} + ct2*2048                    (compile-time immediates)

    bf16x8 kreg[4], vreg[4];
#pragma unroll
    for (int it = 0; it < 4; ++it) {
        kreg[it] = *(const bf16x8*)(kbase + kg[it]);
        vreg[it] = *(const bf16x8*)(vtbase + vg[it]);
    }
#pragma unroll
    for (int it = 0; it < 4; ++it) {
        *(bf16x8*)(Kl + klb[it]) = kreg[it];
        *(bf16x8*)(Vl + vlb[it]) = vreg[it];
    }
    // running pointers (advance once per tile)
    const __bf16* kpt = kbase;
    const __bf16* vpt = vtbase;
    const float* mp = mbase + lg * 8;
    f32x4 mr[4];
#pragma unroll
    for (int ct = 0; ct < 4; ++ct) {
        f32x4 mv = *(const f32x4*)(mp + (ct & 1) * 32 + ((ct >> 1) << 2));
#pragma unroll
        for (int r = 0; r < 4; ++r) mr[ct][r] = mv[r] * LOG2E;
    }

    for (int kv0 = 0; kv0 < 2048; kv0 += 64) {
        __syncthreads();                       // barA: tile kv0 visible in LDS
        const bool more = (kv0 + 64) < 2048;
        if (more) {                            // next-tile loads fly under compute
            kpt += 8192;                       // 64 kv rows * 128 e
            vpt += 64;                         // 64 kv columns
#pragma unroll
            for (int it = 0; it < 4; ++it) {
                kreg[it] = *(const bf16x8*)(kpt + kg[it]);
                vreg[it] = *(const bf16x8*)(vpt + vg[it]);
            }
        }

        // S^T(log2-units) = K Q^T + mask*LOG2E (C-init), permuted rows:
        // st[ct][r] for kv = (ct&1)*32 + lg*8 + (ct>>1)*4 + r, q = l15
        f32x4 st[4];
        __builtin_amdgcn_s_setprio(1);
#pragma unroll
        for (int ct = 0; ct < 4; ++ct) {
            const int co = (ct & 1) * 8192 + (ct >> 1) * 1024;
            f32x4 acc = mr[ct];
            acc = __builtin_amdgcn_mfma_f32_16x16x32_bf16(*(const bf16x8*)(krd0 + co), qf[0], acc, 0, 0, 0);
            acc = __builtin_amdgcn_mfma_f32_16x16x32_bf16(*(const bf16x8*)(krd1 + co), qf[1], acc, 0, 0, 0);
            acc = __builtin_amdgcn_mfma_f32_16x16x32_bf16(*(const bf16x8*)(krd2 + co), qf[2], acc, 0, 0, 0);
            acc = __builtin_amdgcn_mfma_f32_16x16x32_bf16(*(const bf16x8*)(krd3 + co), qf[3], acc, 0, 0, 0);
            st[ct] = acc;
        }
        __builtin_amdgcn_s_setprio(0);

        // pk0 (ct 0,2) -> PV ks2=0; pk1 (ct 1,3) issues under PV-0's shadow.
        union { __bf16 h[8]; bf16x8 v; } pk0, pk1;
#pragma unroll
        for (int ct = 0; ct < 4; ct += 2) {
#pragma unroll
            for (int r = 0; r < 4; ++r) {
                float p = exp2f(st[ct][r]);
                lacc4[r] += p;
                pk0.h[((ct >> 1) << 2) + r] = (__bf16)p;
            }
        }
        __builtin_amdgcn_s_setprio(1);
#pragma unroll
        for (int ct2 = 0; ct2 < 8; ++ct2)
            o_acc[ct2] = __builtin_amdgcn_mfma_f32_16x16x32_bf16(
                *(const bf16x8*)(vrd0 + ct2 * 2048), pk0.v, o_acc[ct2], 0, 0, 0);
        __builtin_amdgcn_s_setprio(0);
#pragma unroll
        for (int ct = 1; ct < 4; ct += 2) {
#pragma unroll
            for (int r = 0; r < 4; ++r) {
                float p = exp2f(st[ct][r]);
                lacc4[r] += p;
                pk1.h[((ct >> 1) << 2) + r] = (__bf16)p;
            }
        }
        __builtin_amdgcn_s_setprio(1);
#pragma unroll
        for (int ct2 = 0; ct2 < 8; ++ct2)
            o_acc[ct2] = __builtin_amdgcn_mfma_f32_16x16x32_bf16(
                *(const bf16x8*)(vrd1 + ct2 * 2048), pk1.v, o_acc[ct2], 0, 0, 0);
        __builtin_amdgcn_s_setprio(0);
        __syncthreads();                       // barC: all reads of Kl/Vl done

        if (more) {                            // stage next tile + next mask
#pragma unroll
            for (int it = 0; it < 4; ++it) {
                *(bf16x8*)(Kl + klb[it]) = kreg[it];
                *(bf16x8*)(Vl + vlb[it]) = vreg[it];
            }
            mp += 64;
#pragma unroll
            for (int ct = 0; ct < 4; ++ct) {
                f32x4 mv = *(const f32x4*)(mp + (ct & 1) * 32 + ((ct >> 1) << 2));
#pragma unroll
                for (int r = 0; r < 4; ++r) mr[ct][r] = mv[r] * LOG2E;
            }
        }
    }

    // epilogue: fold 4 chains, then reduce across lg lanes (2 shuffles)
    float tot = (lacc4[0] + lacc4[1]) + (lacc4[2] + lacc4[3]);
    tot += __shfl_xor(tot, 16);
    tot += __shfl_xor(tot, 32);
    const float linv = 1.0f / tot;
    const size_t tok = (size_t)b * 2048 + q0 + w * 16 + l15;
    __bf16* aop = AO + tok * 1024 + (bh & 7) * 128;
#pragma unroll
    for (int ct2 = 0; ct2 < 8; ++ct2) {
        union { __bf16 h[4]; unsigned long long u64; } ov;
#pragma unroll
        for (int r = 0; r < 4; ++r) ov.h[r] = (__bf16)(o_acc[ct2][r] * linv);
        *(unsigned long long*)(aop + ct2 * 16 + lg * 4) = ov.u64;
    }
}

// ============================================================================
// Kernel C: output projection. 8 tokens/block, thread = (o = tid>>3, t = tid&7).
// ============================================================================
__global__ __launch_bounds__(128) void outproj_kernel(
    const __bf16* __restrict__ AO, const float* __restrict__ wo,
    const float* __restrict__ bo, float* __restrict__ out)
{
    __shared__ float al[8 * 1032];
    const int tid = threadIdx.x;
    const int t0 = blockIdx.x * 8;
#pragma unroll
    for (int it = 0; it < 8; ++it) {
        bf16x8 v = *(const bf16x8*)(AO + (size_t)(t0 + it) * 1024 + tid * 8);
        f32x4 lo = {(float)v[0], (float)v[1], (float)v[2], (float)v[3]};
        f32x4 hi = {(float)v[4], (float)v[5], (float)v[6], (float)v[7]};
        *(f32x4*)(al + it * 1032 + tid * 8) = lo;
        *(f32x4*)(al + it * 1032 + tid * 8 + 4) = hi;
    }
    __syncthreads();
    const int o = tid >> 3, t = tid & 7;
    float acc[8];
    acc[0] = bo[o];
#pragma unroll
    for (int c = 1; c < 8; ++c) acc[c] = 0.f;
    const float4* w4 = (const float4*)wo + o * 128;
    for (int ii = 0; ii < 128; ++ii) {
        float4 wv = w4[ii];
        f32x4 xlo = *(const f32x4*)(al + t * 1032 + ii * 8);
        f32x4 xhi = *(const f32x4*)(al + t * 1032 + ii * 8 + 4);
        float wr[8] = {wv.x, wv.y, wv.y, wv.y, wv.z, wv.z, wv.z, wv.w};
        float xv[8] = {xlo[0], xlo[1], xlo[2], xlo[3], xhi[0], xhi[1], xhi[2], xhi[3]};
#pragma unroll
        for (int c = 0; c < 8; ++c) acc[c] += xv[c] * wr[c];
    }
    float* op = out + (size_t)(t0 + t) * 128 + o * 8;
    *(float4*)op = (float4){acc[0], acc[1], acc[2], acc[3]};
    *(float4*)(op + 4) = (float4){acc[4], acc[5], acc[6], acc[7]};
}

// ============================================================================
extern "C" void kernel_launch(void* const* d_in, const int* in_sizes, int n_in,
                              void* d_out, int out_size, void* d_ws, size_t ws_size,
                              hipStream_t stream)
{
    const float* x    = (const float*)d_in[0];
    const float* mask = (const float*)d_in[1];
    const float* wq   = (const float*)d_in[2];
    const float* bq   = (const float*)d_in[3];
    const float* wk   = (const float*)d_in[4];
    const float* bk   = (const float*)d_in[5];
    const float* wv   = (const float*)d_in[6];
    const float* bv   = (const float*)d_in[7];
    const float* wo   = (const float*)d_in[8];
    const float* bo   = (const float*)d_in[9];
    float* out = (float*)d_out;

    const size_t SLOT = (size_t)32 * 2048 * 128;  // 8M bf16 elems = 16 MiB
    const size_t need = SLOT * 4 * 2;             // 64 MiB
    if (ws_size < need) {
        hipMemsetAsync(d_out, 0, (size_t)out_size * sizeof(float), stream);
        return;
    }
    __bf16* Qg = (__bf16*)d_ws;
    __bf16* Kg = Qg + SLOT;
    __bf16* Vg = Kg + SLOT;   // V row-major; dead after transv
    __bf16* Vt = Vg + SLOT;
    __bf16* AO = Vg;          // reuse: flash writes AO only after Vg is dead

    proj_kernel<<<TOKS / 4, 128, 0, stream>>>(x, wq, bq, wk, bk, wv, bv, Qg, Kg, Vg);
    transv_kernel<<<dim3(32, 32), 256, 0, stream>>>(Vg, Vt);
    flash_kernel<<<dim3(32, 32), 256, 0, stream>>>(Qg, Kg, Vt, mask, AO);
    outproj_kernel<<<TOKS / 8, 128, 0, stream>>>(AO, wo, bo, out);
}